// Round 2
// baseline (601.419 us; speedup 1.0000x reference)
//
#include <hip/hip_runtime.h>

#define T_STEPS 200
#define BATCH   256
#define HCH     2
#define H1      200
#define SPL1    392
#define OCH     4
#define NOUTC   10
#define SPL2    50
#define M_TOTAL (T_STEPS*BATCH)   // 51200

// ---------------------------------------------------------------------
// Workspace layout (bytes):
//   CUR  : [51200][2][200] f32   = 81,920,000
//   S    : [51200][4][52]  u8    = 10,649,600   (52-stride -> 4B-aligned oc slices)
//   CURO : [51200][40]     f32   =  8,192,000   (col = j*4 + oc)
// total ~100.8 MB
// ---------------------------------------------------------------------

// =====================================================================
// Kernel 1: CUR[m,c,n] = sum_i X[m, c*392+i] * Wh[c,n,i] + bh[c,n]
// fp32 VALU GEMM: M=51200, N=200 (grid.y: 2 x BN=100), K=392 (BK=8 x 49)
// BM=80, 256 threads (250 compute), thread tile 8 rows x 4 cols.
// Zero masked FMAs: 80|51200, 100|200, 8|392 all exact.
// =====================================================================
#define BM 80
#define BN 100
#define BK 8

__global__ __launch_bounds__(256)
void k1_gemm(const float* __restrict__ X, const float* __restrict__ Wh,
             const float* __restrict__ bh, float* __restrict__ CUR)
{
    __shared__ float As[BK][BM];   // 2.56 KB
    __shared__ float Ws[BK][BN];   // 3.2 KB  (row stride 400B, 16B-aligned)
    const int tid = threadIdx.x;
    const int m0 = blockIdx.x * BM;
    const int n0 = blockIdx.y * BN;
    const int c  = blockIdx.z;

    const bool active = tid < 250;
    const int rowg = tid / 25;     // 0..9  (8 rows each)
    const int colg = tid % 25;     // 0..24 (4 cols each)

    const float* Xc = X  + (size_t)m0 * (HCH*SPL1) + c*SPL1;
    const float* Wc = Wh + (size_t)c * H1 * SPL1 + (size_t)n0 * SPL1;

    float acc[8][4];
#pragma unroll
    for (int i = 0; i < 8; ++i)
#pragma unroll
        for (int j = 0; j < 4; ++j) acc[i][j] = 0.f;

    for (int k0 = 0; k0 < SPL1; k0 += BK) {
        // A tile: 80 rows x 8 k = 640 floats
        for (int idx = tid; idx < BM*BK; idx += 256) {
            int m = idx >> 3, k = idx & 7;
            As[k][m] = Xc[(size_t)m*(HCH*SPL1) + k0 + k];
        }
        // W tile: 100 cols x 8 k = 800 floats (no mask needed: exact fit)
        for (int idx = tid; idx < BN*BK; idx += 256) {
            int n = idx >> 3, k = idx & 7;
            Ws[k][n] = Wc[(size_t)n*SPL1 + k0 + k];
        }
        __syncthreads();
        if (active) {
#pragma unroll
            for (int k = 0; k < BK; ++k) {
                float4 a0 = *(const float4*)&As[k][rowg*8];
                float4 a1 = *(const float4*)&As[k][rowg*8 + 4];
                float4 w  = *(const float4*)&Ws[k][colg*4];
                float av[8] = {a0.x, a0.y, a0.z, a0.w, a1.x, a1.y, a1.z, a1.w};
                float wv[4] = {w.x, w.y, w.z, w.w};
#pragma unroll
                for (int i = 0; i < 8; ++i)
#pragma unroll
                    for (int j = 0; j < 4; ++j)
                        acc[i][j] = __builtin_fmaf(av[i], wv[j], acc[i][j]);
            }
        }
        __syncthreads();
    }

    if (active) {
        const int gn = n0 + colg*4;
        float4 bias = *(const float4*)&bh[c*H1 + gn];
#pragma unroll
        for (int i = 0; i < 8; ++i) {
            size_t m = m0 + rowg*8 + i;
            float4 v;
            v.x = __fadd_rn(acc[i][0], bias.x);
            v.y = __fadd_rn(acc[i][1], bias.y);
            v.z = __fadd_rn(acc[i][2], bias.z);
            v.w = __fadd_rn(acc[i][3], bias.w);
            *(float4*)&CUR[(m*HCH + c)*H1 + gn] = v;
        }
    }
}

// =====================================================================
// Kernel 2: hidden LIF recurrence, sequential over T, thread = (b,h).
// Depth-8 register prefetch ring (static indices via chunked unroll).
// Exact-order fp32; reset as exact select ((1-z)*vd == z ? 0 : vd).
// =====================================================================
__global__ __launch_bounds__(256)
void k2_lif(const float* __restrict__ CUR, unsigned char* __restrict__ S)
{
    const int tid = blockIdx.x * 256 + threadIdx.x;  // 0..51199
    const int b = tid / H1;
    const int h = tid - b*H1;
    const size_t cbase = (size_t)b*(HCH*H1) + h;          // + t*102400, c*200
    const int    soff  = b*(OCH*52) + (h/SPL2)*52 + (h%SPL2);
    const size_t tstr  = (size_t)BATCH*HCH*H1;            // 102400
    const size_t sstr  = (size_t)BATCH*OCH*52;            // 53248

    float c0[8], c1[8];
#pragma unroll
    for (int p = 0; p < 8; ++p) {
        c0[p] = CUR[(size_t)p*tstr + cbase];
        c1[p] = CUR[(size_t)p*tstr + cbase + H1];
    }

    float vh0 = 0.f, ih0 = 0.f, vh1 = 0.f, ih1 = 0.f;

    for (int tb = 0; tb < T_STEPS; tb += 8) {
#pragma unroll
        for (int u = 0; u < 8; ++u) {
            const int t = tb + u;
            float cc0 = c0[u], cc1 = c1[u];
            if (t + 8 < T_STEPS) {
                c0[u] = CUR[(size_t)(t+8)*tstr + cbase];
                c1[u] = CUR[(size_t)(t+8)*tstr + cbase + H1];
            }
            // vh_dec = vh + 0.1*(ih - vh)
            float vd0 = __fadd_rn(vh0, __fmul_rn(0.1f, __fsub_rn(ih0, vh0)));
            float vd1 = __fadd_rn(vh1, __fmul_rn(0.1f, __fsub_rn(ih1, vh1)));
            // z = heaviside(vh_dec - 1);  (vd-1)>0 <=> vd>1 (exact, Sterbenz)
            int z0 = vd0 > 1.0f;
            int z1 = vd1 > 1.0f;
            // reset: (1-z)*vd
            vh0 = z0 ? 0.f : vd0;
            vh1 = z1 ? 0.f : vd1;
            // ih = 0.8*ih + cur
            ih0 = __fadd_rn(__fmul_rn(ih0, 0.8f), cc0);
            ih1 = __fadd_rn(__fmul_rn(ih1, 0.8f), cc1);

            S[(size_t)t*sstr + soff] = (unsigned char)(z0 + z1);
        }
    }
}

// =====================================================================
// Kernel 3: cur_o[r, j*4+oc] = sum_i s[r,oc,i]*Wo[oc,j,i] + bo[oc,j]
// Register-blocked 4 rows x 5 j per thread. Wo staged in LDS [40][52]
// (b128 reads 8-distinct-bank conflict-free); S read from global as
// u8x4 words (52-stride layout keeps 4B alignment).
// =====================================================================
__global__ __launch_bounds__(256)
void k3_outgemm(const unsigned char* __restrict__ S, const float* __restrict__ Wo,
                const float* __restrict__ bo, float* __restrict__ CURO)
{
    __shared__ float sW[OCH*NOUTC][52];   // row stride 208B (16B-aligned)
    const int tid = threadIdx.x;
    for (int idx = tid; idx < OCH*NOUTC*SPL2; idx += 256)
        sW[idx/SPL2][idx%SPL2] = Wo[idx];
    __syncthreads();

    const int rowg = tid >> 3;          // 0..31
    const int colg = tid & 7;
    const int oc = colg & 3;
    const int jg = colg >> 2;           // 0..1 -> j = jg*5 + jj
    const int cl0 = oc*NOUTC + jg*5;
    const int r0 = blockIdx.x*128 + rowg*4;
    const unsigned char* sp = S + (size_t)r0*(OCH*52) + oc*52;

    float acc[4][5];
#pragma unroll
    for (int rr = 0; rr < 4; ++rr)
#pragma unroll
        for (int jj = 0; jj < 5; ++jj) acc[rr][jj] = 0.f;

#pragma unroll
    for (int q = 0; q < 12; ++q) {
        float4 w0 = *(const float4*)&sW[cl0+0][q*4];
        float4 w1 = *(const float4*)&sW[cl0+1][q*4];
        float4 w2 = *(const float4*)&sW[cl0+2][q*4];
        float4 w3 = *(const float4*)&sW[cl0+3][q*4];
        float4 w4 = *(const float4*)&sW[cl0+4][q*4];
#pragma unroll
        for (int rr = 0; rr < 4; ++rr) {
            unsigned int u = *(const unsigned int*)(sp + (size_t)rr*(OCH*52) + q*4);
            float s0 = (float)(u & 255u);
            float s1 = (float)((u >> 8) & 255u);
            float s2 = (float)((u >> 16) & 255u);
            float s3 = (float)(u >> 24);
            float4 ws[5] = {w0, w1, w2, w3, w4};
#pragma unroll
            for (int jj = 0; jj < 5; ++jj) {
                float a = acc[rr][jj];
                a = __builtin_fmaf(s0, ws[jj].x, a);
                a = __builtin_fmaf(s1, ws[jj].y, a);
                a = __builtin_fmaf(s2, ws[jj].z, a);
                a = __builtin_fmaf(s3, ws[jj].w, a);
                acc[rr][jj] = a;
            }
        }
    }
    // tail i = 48,49
#pragma unroll
    for (int rr = 0; rr < 4; ++rr) {
        unsigned short ut = *(const unsigned short*)(sp + (size_t)rr*(OCH*52) + 48);
        float s48 = (float)(ut & 255u);
        float s49 = (float)(ut >> 8);
#pragma unroll
        for (int jj = 0; jj < 5; ++jj) {
            float2 wt = *(const float2*)&sW[cl0+jj][48];
            float a = acc[rr][jj];
            a = __builtin_fmaf(s48, wt.x, a);
            a = __builtin_fmaf(s49, wt.y, a);
            acc[rr][jj] = a;
        }
    }
#pragma unroll
    for (int rr = 0; rr < 4; ++rr)
#pragma unroll
        for (int jj = 0; jj < 5; ++jj) {
            int j = jg*5 + jj;
            CURO[(size_t)(r0+rr)*(OCH*NOUTC) + j*4 + oc] =
                __fadd_rn(acc[rr][jj], bo[oc*NOUTC + j]);
        }
}

// =====================================================================
// Kernel 4: output LI recurrence + oc-sum. Thread = (b,j) owns the 4 oc
// channels as one float4 column; depth-8 float4 prefetch ring.
// v[t] from vo_new (old io), io_new from cur_o[t]; sequential oc-sum.
// =====================================================================
__global__ __launch_bounds__(64)
void k4_li(const float* __restrict__ CURO, float* __restrict__ OUT)
{
    const int tid = blockIdx.x*64 + threadIdx.x;   // 0..2559 = b*10+j
    const float4* C4 = (const float4*)CURO;        // row = 2560 float4s

    float4 ring[8];
#pragma unroll
    for (int p = 0; p < 8; ++p) ring[p] = C4[(size_t)p*2560 + tid];

    float vo0=0.f, vo1=0.f, vo2=0.f, vo3=0.f;
    float io0=0.f, io1=0.f, io2=0.f, io3=0.f;

    for (int tb = 0; tb < T_STEPS; tb += 8) {
#pragma unroll
        for (int u = 0; u < 8; ++u) {
            const int t = tb + u;
            float4 cv = ring[u];
            if (t + 8 < T_STEPS) ring[u] = C4[(size_t)(t+8)*2560 + tid];
            vo0 = __fadd_rn(vo0, __fmul_rn(0.1f, __fsub_rn(io0, vo0)));
            vo1 = __fadd_rn(vo1, __fmul_rn(0.1f, __fsub_rn(io1, vo1)));
            vo2 = __fadd_rn(vo2, __fmul_rn(0.1f, __fsub_rn(io2, vo2)));
            vo3 = __fadd_rn(vo3, __fmul_rn(0.1f, __fsub_rn(io3, vo3)));
            io0 = __fadd_rn(__fmul_rn(io0, 0.8f), cv.x);
            io1 = __fadd_rn(__fmul_rn(io1, 0.8f), cv.y);
            io2 = __fadd_rn(__fmul_rn(io2, 0.8f), cv.z);
            io3 = __fadd_rn(__fmul_rn(io3, 0.8f), cv.w);
            float s = __fadd_rn(__fadd_rn(__fadd_rn(vo0, vo1), vo2), vo3);
            OUT[(size_t)t*2560 + tid] = s;
        }
    }
}

// =====================================================================
extern "C" void kernel_launch(void* const* d_in, const int* in_sizes, int n_in,
                              void* d_out, int out_size, void* d_ws, size_t ws_size,
                              hipStream_t stream)
{
    const float* X  = (const float*)d_in[0];   // [200,256,28,28]
    const float* Wh = (const float*)d_in[1];   // [2,200,392]
    const float* bh = (const float*)d_in[2];   // [2,200]
    const float* Wo = (const float*)d_in[3];   // [4,10,50]
    const float* bo = (const float*)d_in[4];   // [4,10]
    float* OUT = (float*)d_out;                // [200,256,10]

    char* ws = (char*)d_ws;
    float*         CUR  = (float*)ws;                               // 81,920,000
    unsigned char* S    = (unsigned char*)(ws + 81920000);          // 10,649,600
    float*         CURO = (float*)(ws + 81920000 + 10649600);       //  8,192,000

    k1_gemm   <<<dim3(M_TOTAL/BM, 2, HCH), 256, 0, stream>>>(X, Wh, bh, CUR);
    k2_lif    <<<M_TOTAL/256,              256, 0, stream>>>(CUR, S);
    k3_outgemm<<<M_TOTAL/128,              256, 0, stream>>>(S, Wo, bo, CURO);
    k4_li     <<<(BATCH*NOUTC)/64,         64,  0, stream>>>(CURO, OUT);
}